// Round 11
// baseline (770.380 us; speedup 1.0000x reference)
//
#include <hip/hip_runtime.h>

// Entropic Sinkhorn EMD, B=2, N=4096, D=3, EPS=0.1, 20 iters.
// Round-11: fused kernel; R10's 4-leg hierarchical barrier replaced by
// direct publish counters: producers fire-and-forget ONE system-scope
// fetch_add per block per sweep (8 group counters/batch, 32 adds each);
// consumers poll with ABSOLUTE targets (counters reset to 0 at kernel end
// by block 0 after a done-count -- provably quiescent, so no base-read race
// across graph replays). h2 exchange is parity double-buffered in ws;
// overwrite safety follows from the counter ordering. Co-residency by
// capacity: 512 blocks x 512 thr, <=128 VGPR -> 2 blocks/CU x 256 CU.

#define N    4096
#define NT   512
#define RPB  16     // rows per block
#define NBLK 512    // 256 row-blocks per batch x 2 batches
#define NW   (NT / 64)
#define KIT  (N / NT)

constexpr float EPS_F  = 0.1f;
constexpr float SHIFT  = 60.0f;
constexpr float LOG_A  = -8.317766166719343f;   // -log(4096)
constexpr float C10L   = 14.426950408889634f;   // 10*log2(e)
constexpr float C20L   = 28.853900817779268f;   // 20*log2(e)
constexpr float SHIFTL = 86.56170245333781f;    // SHIFT*log2(e)
constexpr float NLN2T  = -0.06931471805599453f; // -ln2/10
constexpr float LN2    = 0.6931471805599453f;

extern "C" __device__ float __ocml_native_exp2_f32(float);

__device__ __forceinline__ float fast_exp2(float x) {
#if __has_builtin(__builtin_amdgcn_exp2f)
    return __builtin_amdgcn_exp2f(x);
#else
    return __ocml_native_exp2_f32(x);
#endif
}

__device__ __forceinline__ float rfl(float x) {
    return __int_as_float(__builtin_amdgcn_readfirstlane(__float_as_int(x)));
}

// System-scope relaxed ops (served at the die-level coherence point).
#define ALOADF(p)    __hip_atomic_load((p), __ATOMIC_RELAXED, __HIP_MEMORY_SCOPE_SYSTEM)
#define ALOADU(p)    __hip_atomic_load((p), __ATOMIC_RELAXED, __HIP_MEMORY_SCOPE_SYSTEM)
#define ASTOREF(p,v) __hip_atomic_store((p), (v), __ATOMIC_RELAXED, __HIP_MEMORY_SCOPE_SYSTEM)
#define ASTOREU(p,v) __hip_atomic_store((p), (v), __ATOMIC_RELAXED, __HIP_MEMORY_SCOPE_SYSTEM)
#define AADD_NR(p)   (void)__hip_atomic_fetch_add((p), 1u, __ATOMIC_RELAXED, __HIP_MEMORY_SCOPE_SYSTEM)
#define VMWAIT()     asm volatile("s_waitcnt vmcnt(0)" ::: "memory")

// Publish counters: __device__ globals (zero at load; block 0 resets them to
// zero at kernel end, after proving quiescence via g_done). Absolute targets.
struct alignas(128) PadU { unsigned int v; unsigned int pad[31]; };
__device__ PadU g_prep[8];        // 512 adds total (64 per bucket)
__device__ PadU g_cntF[2][8];     // per batch, per group-of-32-blocks
__device__ PadU g_cntG[2][8];
__device__ PadU g_done[8];        // 512 adds total

// Poll 8 counters until all >= tgt. Thread-0 only; one RT per round.
__device__ __forceinline__ void wait8(PadU* a, unsigned tgt) {
    for (;;) {
        unsigned m0 = ALOADU(&a[0].v), m1 = ALOADU(&a[1].v);
        unsigned m2 = ALOADU(&a[2].v), m3 = ALOADU(&a[3].v);
        unsigned m4 = ALOADU(&a[4].v), m5 = ALOADU(&a[5].v);
        unsigned m6 = ALOADU(&a[6].v), m7 = ALOADU(&a[7].v);
        unsigned mn = min(min(min(m0, m1), min(m2, m3)),
                          min(min(m4, m5), min(m6, m7)));
        if (mn >= tgt) break;
        __builtin_amdgcn_s_sleep(2);
    }
}

// One half-sweep over this block's RPB rows. Row constants in SGPRs (cached
// immutable pts); column h2 via KIT up-front scoped loads (coherent);
// column xyz via cached float4 loads. Epilogue scoped-stores raw dual +
// next h2 (parity buffer), VMWAITs, then fire-and-forget publishes.
__device__ __forceinline__ void half_sweep(
    const float4* ptsRow, const float4* ptsCol,
    const float* h2ColIn, float* h2RowOut, float* dualOut,
    PadU* pubCnt, int b, int rowBase, int tid)
{
    const float4* rp = ptsRow + (size_t)b * N + rowBase;

    float X[RPB], Y[RPB], Z[RPB], S[RPB];
    #pragma unroll
    for (int r = 0; r < RPB; ++r) {
        float4 q = rp[r];
        X[r] = rfl(q.x * C20L);
        Y[r] = rfl(q.y * C20L);
        Z[r] = rfl(q.z * C20L);
        S[r] = rfl(q.w);                   // -10L|p_i|^2
    }

    const float4* cp = ptsCol + (size_t)b * N;

    float h2k[KIT];
    #pragma unroll
    for (int k = 0; k < KIT; ++k) h2k[k] = ALOADF(&h2ColIn[tid + NT * k]);

    float acc[RPB];
    #pragma unroll
    for (int r = 0; r < RPB; ++r) acc[r] = 0.0f;

    #pragma unroll
    for (int k = 0; k < KIT; ++k) {
        float4 p = cp[tid + NT * k];       // cached (immutable)
        float hv = h2k[k];
        #pragma unroll
        for (int r = 0; r < RPB; ++r) {
            float t = fmaf(Z[r], p.z, hv);
            t = fmaf(Y[r], p.y, t);
            t = fmaf(X[r], p.x, t);
            acc[r] += fast_exp2(t + S[r]);
        }
    }

    #pragma unroll
    for (int r = 0; r < RPB; ++r) {
        float a = acc[r];
        a += __shfl_xor(a, 32);
        a += __shfl_xor(a, 16);
        a += __shfl_xor(a, 8);
        a += __shfl_xor(a, 4);
        a += __shfl_xor(a, 2);
        a += __shfl_xor(a, 1);
        acc[r] = a;
    }
    __shared__ float sred[RPB][NW];
    const int wave = tid >> 6, lane = tid & 63;
    if (lane == 0) {
        #pragma unroll
        for (int r = 0; r < RPB; ++r) sred[r][wave] = acc[r];
    }
    __syncthreads();
    if (tid < RPB) {       // wave 0 only
        float s = 0.f;
        #pragma unroll
        for (int w = 0; w < NW; ++w) s += sred[tid][w];
        float dual = EPS_F * (LOG_A + SHIFT - log2f(s) * LN2);
        float nb = rp[tid].w;
        ASTOREF(&dualOut[(size_t)b * N + rowBase + tid], dual);
        ASTOREF(&h2RowOut[rowBase + tid], fmaf(dual, C10L, SHIFTL + nb));
    }
    if (tid == 0) {        // same wave as the stores above
        VMWAIT();          // h2/dual stores are globally visible...
        AADD_NR(&pubCnt->v);   // ...before the publish (no return wait)
    }
}

__global__ __launch_bounds__(NT, 4) void fused_kernel(
    const float* __restrict__ gen, const float* __restrict__ gt,
    float4* ptsGen, float4* ptsGt,
    float* h2F, float* h2G,      // [2 batches][2 parity][N]
    float* f, float* g,
    float* out)
{
    const int tid = threadIdx.x;
    const int blk = blockIdx.x;        // 0..511
    const int b   = blk >> 8;          // batch
    const int r   = blk & 255;         // row-chunk
    const int rowBase = r * RPB;
    const int grp = r >> 5;            // publish group (32 blocks each)

    // ---- prep: pts {x,y,z,-10L|p|^2}; h2G init (parity 1, duals=0); out=0
    {
        int t = blk * NT + tid;
        if (t < 16384) {
            int cloud = t >> 13;
            int idx   = t & 8191;      // b*N + j
            const float* src = cloud ? gt : gen;
            float x = src[idx * 3 + 0];
            float y = src[idx * 3 + 1];
            float z = src[idx * 3 + 2];
            float nb = -C10L * fmaf(z, z, fmaf(y, y, x * x));
            float* P = (float*)((cloud ? ptsGt : ptsGen) + idx);
            ASTOREF(&P[0], x);
            ASTOREF(&P[1], y);
            ASTOREF(&P[2], z);
            ASTOREF(&P[3], nb);
            if (cloud) {               // h2(g=0) for gt, parity 1
                int bb = idx >> 12, j = idx & 4095;
                ASTOREF(&h2G[(bb * 2 + 1) * N + j], SHIFTL + nb);
            }
            if (t == 0) ASTOREF(out, 0.0f);
        }
    }
    VMWAIT();
    __syncthreads();
    if (tid == 0) {
        AADD_NR(&g_prep[blk & 7].v);
        wait8(g_prep, 64u);
    }
    __syncthreads();

    for (int it = 0; it < 20; ++it) {
        // f(it): rows=gen, cols=gt; reads h2G parity (it-1)&1; writes h2F it&1
        if (it > 0) {
            if (tid == 0) wait8(g_cntG[b], 32u * (unsigned)it);
            __syncthreads();
        }
        half_sweep(ptsGen, ptsGt,
                   h2G + (b * 2 + ((it - 1) & 1)) * N,
                   h2F + (b * 2 + (it & 1)) * N,
                   f, &g_cntF[b][grp], b, rowBase, tid);
        // g(it): rows=gt, cols=gen; reads h2F it&1; writes h2G it&1
        if (tid == 0) wait8(g_cntF[b], 32u * (unsigned)(it + 1));
        __syncthreads();
        half_sweep(ptsGt, ptsGen,
                   h2F + (b * 2 + (it & 1)) * N,
                   h2G + (b * 2 + (it & 1)) * N,
                   g, &g_cntG[b][grp], b, rowBase, tid);
    }

    // ---- loss: wait all g(19), then += 0.5*sum exp((f+g-C)/EPS)*C
    if (tid == 0) wait8(g_cntG[b], 640u);
    __syncthreads();
    {
        const float4* rp = ptsGen + (size_t)b * N + rowBase;
        const float*  fp = f      + (size_t)b * N + rowBase;

        float Ax[RPB], Ay[RPB], Az[RPB], Ri[RPB], F2[RPB];
        #pragma unroll
        for (int rr = 0; rr < RPB; ++rr) {
            float4 q = rp[rr];
            Ax[rr] = rfl(q.x * -2.0f);
            Ay[rr] = rfl(q.y * -2.0f);
            Az[rr] = rfl(q.z * -2.0f);
            Ri[rr] = rfl(q.w * NLN2T);         // |p_i|^2
            F2[rr] = rfl(ALOADF((float*)&fp[rr]) * C10L);
        }

        const float4* cp = ptsGt + (size_t)b * N;
        const float*  gc = g     + (size_t)b * N;

        float gk[KIT];
        #pragma unroll
        for (int k = 0; k < KIT; ++k) gk[k] = ALOADF((float*)&gc[tid + NT * k]);

        float acc = 0.0f;
        #pragma unroll
        for (int k = 0; k < KIT; ++k) {
            float4 p  = cp[tid + NT * k];
            float  G2 = gk[k] * C10L;
            float  rj = p.w * NLN2T;           // |p_j|^2
            #pragma unroll
            for (int rr = 0; rr < RPB; ++rr) {
                float cc = rj + Ri[rr];
                cc = fmaf(Az[rr], p.z, cc);
                cc = fmaf(Ay[rr], p.y, cc);
                cc = fmaf(Ax[rr], p.x, cc);
                float arg = fmaf(cc, -C10L, G2 + F2[rr]);
                acc = fmaf(fast_exp2(arg), cc, acc);
            }
        }

        acc += __shfl_xor(acc, 32);
        acc += __shfl_xor(acc, 16);
        acc += __shfl_xor(acc, 8);
        acc += __shfl_xor(acc, 4);
        acc += __shfl_xor(acc, 2);
        acc += __shfl_xor(acc, 1);
        __shared__ float sredL[NW];
        const int wave = tid >> 6, lane = tid & 63;
        if (lane == 0) sredL[wave] = acc;
        __syncthreads();
        if (tid == 0) {
            float t = 0.f;
            #pragma unroll
            for (int w = 0; w < NW; ++w) t += sredL[w];
            __hip_atomic_fetch_add(out, t * 0.5f, __ATOMIC_RELAXED,
                                   __HIP_MEMORY_SCOPE_SYSTEM);
        }
    }

    // ---- done protocol: prove quiescence, then block 0 resets counters to 0
    // (every earlier add was observed by some wait8 before the matching done
    // add, so all counters are quiescent when g_done hits 512).
    if (tid == 0) {
        AADD_NR(&g_done[blk & 7].v);
        if (blk == 0) {
            wait8(g_done, 64u);
            #pragma unroll
            for (int i = 0; i < 8; ++i) {
                ASTOREU(&g_prep[i].v, 0u);
                ASTOREU(&g_done[i].v, 0u);
                ASTOREU(&g_cntF[0][i].v, 0u);
                ASTOREU(&g_cntF[1][i].v, 0u);
                ASTOREU(&g_cntG[0][i].v, 0u);
                ASTOREU(&g_cntG[1][i].v, 0u);
            }
            VMWAIT();
        }
    }
}

extern "C" void kernel_launch(void* const* d_in, const int* in_sizes, int n_in,
                              void* d_out, int out_size, void* d_ws, size_t ws_size,
                              hipStream_t stream) {
    const float* gen = (const float*)d_in[0];
    const float* gt  = (const float*)d_in[1];
    float* out = (float*)d_out;

    char* ws = (char*)d_ws;
    float4* ptsGen = (float4*)ws;                    // 128 KB [2][N]
    float4* ptsGt  = (float4*)(ws + 128 * 1024);     // 128 KB
    float*  h2F    = (float*)(ws + 256 * 1024);      // 64 KB [2][2][N]
    float*  h2G    = (float*)(ws + 320 * 1024);      // 64 KB [2][2][N]
    float*  f      = (float*)(ws + 384 * 1024);      // 32 KB [2][N]
    float*  g      = (float*)(ws + 416 * 1024);      // 32 KB [2][N]

    fused_kernel<<<dim3(NBLK), dim3(NT), 0, stream>>>(
        gen, gt, ptsGen, ptsGt, h2F, h2G, f, g, out);
}